// Round 3
// baseline (834.873 us; speedup 1.0000x reference)
//
#include <hip/hip_runtime.h>

// VIF SSIM loss: per-11x11-block stats of three f32 images, SSIM score, mean.
// R1: latency-bound at 12 waves/CU (LDS 45.5KB). R2: forcing occupancy via
// __launch_bounds__(384,6) spilled accumulators (VGPR 40, 207MB scratch writes).
// R3: 16 scalar accumulators (per-row l/r fold), 256-thr blocks, VGPR cap 85
//     -> 16.5KB LDS, no spill, ~24 waves/CU.

namespace {
constexpr int K      = 11;
constexpr int W      = 1408;
constexpr int H      = 1408;
constexpr int B      = 16;
constexpr int BPR    = W / K;   // 128 blocks per row
constexpr int BROWS  = H / K;   // 128 block rows
constexpr int CHUNKS = W / 4;   // 352 float4 chunks per image row
constexpr float C_C  = 0.0009f;
constexpr float INV_KK = 1.0f / (float)(K * K);
}

// l += dot(a, wl); r += dot(a, wr)   (wr = 1 - wl componentwise)
__device__ __forceinline__ void accsplit(float& l, float& r, const float4 a,
                                         const float4 wl, const float4 wr) {
    l += a.x * wl.x + a.y * wl.y + a.z * wl.z + a.w * wl.w;
    r += a.x * wr.x + a.y * wr.y + a.z * wr.z + a.w * wr.w;
}

__global__ __launch_bounds__(256, 6) void vif_pass1(
    const float* __restrict__ vis,
    const float* __restrict__ ir,
    const float* __restrict__ fus,
    double* __restrict__ accum)
{
    // Per-BLOCK partial sums: 8 quantities x 4 slots x 128 blocks = 16 KB.
    // Slot = chunk&3: the <=4 consecutive chunks overlapping a block get
    // distinct slots -> no atomics, deterministic (verified R2, absmax 0).
    __shared__ float s[8][4][BPR];
    __shared__ float wsum[4];

    const int t  = threadIdx.x;
    const int b  = blockIdx.x >> 7;    // batch (grid = B*BROWS, BROWS=128)
    const int br = blockIdx.x & 127;   // block row
    const size_t strip = (size_t)b * ((size_t)H * W) + (size_t)br * K * W;

    // Zero the partial-sum LDS (slots not covered by any chunk stay 0).
    for (int i = t; i < 8 * 4 * BPR; i += 256) ((float*)s)[i] = 0.f;
    __syncthreads();

    for (int c = t; c < CHUNKS; c += 256) {
        const int bl = (4 * c) / K;            // left block index
        const int nb = K * (bl + 1) - 4 * c;   // #cols in left block (1..11)
        const float4 wl = make_float4(1.f, nb > 1 ? 1.f : 0.f,
                                      nb > 2 ? 1.f : 0.f, nb > 3 ? 1.f : 0.f);
        const float4 wr = make_float4(0.f, 1.f - wl.y, 1.f - wl.z, 1.f - wl.w);

        // 16 scalar accumulators: left/right block per quantity.
        float lv = 0.f, rv = 0.f, lv2 = 0.f, rv2 = 0.f;
        float li = 0.f, ri = 0.f, li2 = 0.f, ri2 = 0.f;
        float lf = 0.f, rf = 0.f, lf2 = 0.f, rf2 = 0.f;
        float lvf = 0.f, rvf = 0.f, lif = 0.f, rif = 0.f;

        const size_t base = strip + (size_t)c * 4;
#pragma unroll
        for (int r = 0; r < K; ++r) {
            const size_t o = base + (size_t)r * W;
            const float4 v = *(const float4*)(vis + o);
            const float4 i = *(const float4*)(ir  + o);
            const float4 f = *(const float4*)(fus + o);
            accsplit(lv,  rv,  v, wl, wr);
            accsplit(lv2, rv2, make_float4(v.x*v.x, v.y*v.y, v.z*v.z, v.w*v.w), wl, wr);
            accsplit(li,  ri,  i, wl, wr);
            accsplit(li2, ri2, make_float4(i.x*i.x, i.y*i.y, i.z*i.z, i.w*i.w), wl, wr);
            accsplit(lf,  rf,  f, wl, wr);
            accsplit(lf2, rf2, make_float4(f.x*f.x, f.y*f.y, f.z*f.z, f.w*f.w), wl, wr);
            accsplit(lvf, rvf, make_float4(v.x*f.x, v.y*f.y, v.z*f.z, v.w*f.w), wl, wr);
            accsplit(lif, rif, make_float4(i.x*f.x, i.y*f.y, i.z*f.z, i.w*f.w), wl, wr);
        }

        const int sl = c & 3;
        s[0][sl][bl] = lv;  s[1][sl][bl] = lv2;
        s[2][sl][bl] = li;  s[3][sl][bl] = li2;
        s[4][sl][bl] = lf;  s[5][sl][bl] = lf2;
        s[6][sl][bl] = lvf; s[7][sl][bl] = lif;
        if (nb < 4) {       // some columns spill into block bl+1
            s[0][sl][bl + 1] = rv;  s[1][sl][bl + 1] = rv2;
            s[2][sl][bl + 1] = ri;  s[3][sl][bl + 1] = ri2;
            s[4][sl][bl + 1] = rf;  s[5][sl][bl + 1] = rf2;
            s[6][sl][bl + 1] = rvf; s[7][sl][bl + 1] = rif;
        }
    }
    __syncthreads();

    // ---- Phase 2: fold 4 slots per block, compute score ----
    float score = 0.0f;
    if (t < BPR) {
        float a[8];
#pragma unroll
        for (int q = 0; q < 8; ++q)   // lane-consecutive reads: conflict-free
            a[q] = s[q][0][t] + s[q][1][t] + s[q][2][t] + s[q][3][t];

        const float vm  = a[0] * INV_KK;
        const float vs2 = a[1] * INV_KK;
        const float im  = a[2] * INV_KK;
        const float is2 = a[3] * INV_KK;
        const float fm  = a[4] * INV_KK;
        const float fs2 = a[5] * INV_KK;
        const float vfm = a[6] * INV_KK;
        const float ifm = a[7] * INV_KK;

        const float vv = fabsf(vs2 - vm * vm);
        const float iv = fabsf(is2 - im * im);
        const float fv = fabsf(fs2 - fm * fm);
        const float vf_cov = vfm - vm * fm;
        const float if_cov = ifm - im * fm;

        const float l_vf = (2.f * vm * fm + C_C) / (vm * vm + fm * fm + C_C);
        const float l_if = (2.f * im * fm + C_C) / (im * im + fm * fm + C_C);
        const float s_vf = (vf_cov + C_C) / (vv + fv + C_C);
        const float s_if = (if_cov + C_C) / (iv + fv + C_C);

        score = (vm > im) ? (l_vf * s_vf) : (l_if * s_if);
    }

    // ---- Reduce scores across the workgroup -> one atomic ----
#pragma unroll
    for (int o = 32; o > 0; o >>= 1) score += __shfl_down(score, o, 64);
    if ((t & 63) == 0) wsum[t >> 6] = score;
    __syncthreads();
    if (t == 0) {
        const double tot = (double)wsum[0] + (double)wsum[1]
                         + (double)wsum[2] + (double)wsum[3];
        atomicAdd(accum, tot);
    }
}

__global__ void vif_finalize(const double* __restrict__ accum,
                             float* __restrict__ out)
{
    if (threadIdx.x == 0 && blockIdx.x == 0) {
        out[0] = 1.0f - (float)(accum[0] / (double)(B * BROWS * BPR));
    }
}

extern "C" void kernel_launch(void* const* d_in, const int* in_sizes, int n_in,
                              void* d_out, int out_size, void* d_ws, size_t ws_size,
                              hipStream_t stream) {
    const float* vis = (const float*)d_in[0];
    const float* ir  = (const float*)d_in[1];
    const float* fus = (const float*)d_in[2];
    float* out = (float*)d_out;
    double* accum = (double*)d_ws;

    // d_ws is re-poisoned to 0xAA before every timed launch; zero it.
    hipMemsetAsync(accum, 0, sizeof(double), stream);
    vif_pass1<<<dim3(B * BROWS), dim3(256), 0, stream>>>(vis, ir, fus, accum);
    vif_finalize<<<dim3(1), dim3(64), 0, stream>>>(accum, out);
}

// Round 4
// 332.966 us; speedup vs baseline: 2.5074x; 2.5074x over previous
//
#include <hip/hip_runtime.h>

// VIF SSIM loss: per-11x11-block stats of three f32 images, SSIM score, mean.
// History: R1 128us (no-spill VGPR84, but LDS 45.5KB -> 12 waves/CU, latency-
// bound: warm-L3 replay identical time). R2/R3 regressed: __launch_bounds__
// min-waves arg (,6) clamped VGPR to 40 -> 0.9-1.6 GB scratch spill traffic.
// R4: R2 datapath (float4 accumulators, end-of-loop l/r fold, 16.9KB LDS)
// with NO min-wave forcing -> natural VGPR ~84, 24 waves/CU, zero spill.

namespace {
constexpr int K      = 11;
constexpr int W      = 1408;
constexpr int H      = 1408;
constexpr int B      = 16;
constexpr int BPR    = W / K;   // 128 blocks per row
constexpr int BROWS  = H / K;   // 128 block rows
constexpr int CHUNKS = W / 4;   // 352 float4 chunks per image row
constexpr float C_C  = 0.0009f;
constexpr float INV_KK = 1.0f / (float)(K * K);
}

__device__ __forceinline__ void acc4(float4& a, const float4 v) {
    a.x += v.x; a.y += v.y; a.z += v.z; a.w += v.w;
}
__device__ __forceinline__ void fma4(float4& a, const float4 u, const float4 v) {
    a.x += u.x * v.x; a.y += u.y * v.y; a.z += u.z * v.z; a.w += u.w * v.w;
}

// Split a float4 column-sum into left-block / right-block contributions.
// nb = #leading components belonging to the left block (1..11; >=4 => all left).
__device__ __forceinline__ void split4(const float4 a, const int nb,
                                       float& l, float& r) {
    l = a.x;
    r = 0.f;
    if (nb > 1) l += a.y; else r += a.y;
    if (nb > 2) l += a.z; else r += a.z;
    if (nb > 3) l += a.w; else r += a.w;
}

// NOTE: no min-waves arg! (,6) clamps VGPR to 40 and spills ~1GB (R2/R3).
__global__ __launch_bounds__(384) void vif_pass1(
    const float* __restrict__ vis,
    const float* __restrict__ ir,
    const float* __restrict__ fus,
    double* __restrict__ accum)
{
    // Per-BLOCK partial sums: 8 quantities x 4 slots x 128 blocks = 16 KB.
    // Slot = chunk&3: the <=4 consecutive chunks overlapping a block get
    // distinct slots -> no atomics, deterministic (verified R2/R3, absmax 0).
    __shared__ float s[8][4][BPR];
    __shared__ float wsum[6];

    const int t  = threadIdx.x;
    const int b  = blockIdx.x >> 7;    // batch (grid = B*BROWS, BROWS=128)
    const int br = blockIdx.x & 127;   // block row

    // Zero the partial-sum LDS (slots not covered by any chunk stay 0).
    for (int i = t; i < 8 * 4 * BPR; i += 384) ((float*)s)[i] = 0.f;
    __syncthreads();

    if (t < CHUNKS) {
        const size_t base = (size_t)b * ((size_t)H * W) + (size_t)br * K * W
                          + (size_t)t * 4;
        float4 sv  = make_float4(0.f, 0.f, 0.f, 0.f);
        float4 sv2 = make_float4(0.f, 0.f, 0.f, 0.f);
        float4 si  = make_float4(0.f, 0.f, 0.f, 0.f);
        float4 si2 = make_float4(0.f, 0.f, 0.f, 0.f);
        float4 sf  = make_float4(0.f, 0.f, 0.f, 0.f);
        float4 sf2 = make_float4(0.f, 0.f, 0.f, 0.f);
        float4 svf = make_float4(0.f, 0.f, 0.f, 0.f);
        float4 sif = make_float4(0.f, 0.f, 0.f, 0.f);
#pragma unroll
        for (int r = 0; r < K; ++r) {
            const size_t o = base + (size_t)r * W;
            const float4 v = *(const float4*)(vis + o);
            const float4 i = *(const float4*)(ir  + o);
            const float4 f = *(const float4*)(fus + o);
            acc4(sv, v);
            fma4(sv2, v, v);
            acc4(si, i);
            fma4(si2, i, i);
            acc4(sf, f);
            fma4(sf2, f, f);
            fma4(svf, v, f);
            fma4(sif, i, f);
        }
        // Fold the 4 columns into per-block contributions (once, not per-row).
        const int bl = (4 * t) / K;            // left block index
        const int nb = K * (bl + 1) - 4 * t;   // #cols in left block
        const int sl = t & 3;
        float l, r;
        split4(sv,  nb, l, r); s[0][sl][bl] = l; if (nb < 4) s[0][sl][bl + 1] = r;
        split4(sv2, nb, l, r); s[1][sl][bl] = l; if (nb < 4) s[1][sl][bl + 1] = r;
        split4(si,  nb, l, r); s[2][sl][bl] = l; if (nb < 4) s[2][sl][bl + 1] = r;
        split4(si2, nb, l, r); s[3][sl][bl] = l; if (nb < 4) s[3][sl][bl + 1] = r;
        split4(sf,  nb, l, r); s[4][sl][bl] = l; if (nb < 4) s[4][sl][bl + 1] = r;
        split4(sf2, nb, l, r); s[5][sl][bl] = l; if (nb < 4) s[5][sl][bl + 1] = r;
        split4(svf, nb, l, r); s[6][sl][bl] = l; if (nb < 4) s[6][sl][bl + 1] = r;
        split4(sif, nb, l, r); s[7][sl][bl] = l; if (nb < 4) s[7][sl][bl + 1] = r;
    }
    __syncthreads();

    // ---- Phase 2: fold 4 slots per block, compute score ----
    float score = 0.0f;
    if (t < BPR) {
        float a[8];
#pragma unroll
        for (int q = 0; q < 8; ++q)   // lane-consecutive reads: conflict-free
            a[q] = s[q][0][t] + s[q][1][t] + s[q][2][t] + s[q][3][t];

        const float vm  = a[0] * INV_KK;
        const float vs2 = a[1] * INV_KK;
        const float im  = a[2] * INV_KK;
        const float is2 = a[3] * INV_KK;
        const float fm  = a[4] * INV_KK;
        const float fs2 = a[5] * INV_KK;
        const float vfm = a[6] * INV_KK;
        const float ifm = a[7] * INV_KK;

        const float vv = fabsf(vs2 - vm * vm);
        const float iv = fabsf(is2 - im * im);
        const float fv = fabsf(fs2 - fm * fm);
        const float vf_cov = vfm - vm * fm;
        const float if_cov = ifm - im * fm;

        const float l_vf = (2.f * vm * fm + C_C) / (vm * vm + fm * fm + C_C);
        const float l_if = (2.f * im * fm + C_C) / (im * im + fm * fm + C_C);
        const float s_vf = (vf_cov + C_C) / (vv + fv + C_C);
        const float s_if = (if_cov + C_C) / (iv + fv + C_C);

        score = (vm > im) ? (l_vf * s_vf) : (l_if * s_if);
    }

    // ---- Reduce scores across the workgroup -> one atomic ----
#pragma unroll
    for (int o = 32; o > 0; o >>= 1) score += __shfl_down(score, o, 64);
    if ((t & 63) == 0) wsum[t >> 6] = score;
    __syncthreads();
    if (t == 0) {
        double tot = 0.0;
#pragma unroll
        for (int wv = 0; wv < 6; ++wv) tot += (double)wsum[wv];
        atomicAdd(accum, tot);
    }
}

__global__ void vif_finalize(const double* __restrict__ accum,
                             float* __restrict__ out)
{
    if (threadIdx.x == 0 && blockIdx.x == 0) {
        out[0] = 1.0f - (float)(accum[0] / (double)(B * BROWS * BPR));
    }
}

extern "C" void kernel_launch(void* const* d_in, const int* in_sizes, int n_in,
                              void* d_out, int out_size, void* d_ws, size_t ws_size,
                              hipStream_t stream) {
    const float* vis = (const float*)d_in[0];
    const float* ir  = (const float*)d_in[1];
    const float* fus = (const float*)d_in[2];
    float* out = (float*)d_out;
    double* accum = (double*)d_ws;

    // d_ws is re-poisoned to 0xAA before every timed launch; zero it.
    hipMemsetAsync(accum, 0, sizeof(double), stream);
    vif_pass1<<<dim3(B * BROWS), dim3(384), 0, stream>>>(vis, ir, fus, accum);
    vif_finalize<<<dim3(1), dim3(64), 0, stream>>>(accum, out);
}